// Round 12
// baseline (18929.738 us; speedup 1.0000x reference)
//
#include <hip/hip_runtime.h>

#define HID     32
#define SLEN    65536
#define NB      32
#define BSTEP   64                 // steps per block = lanes of x per load
#define NBLK    (SLEN / BSTEP)
#define RSTRIDE 36                 // floats per ring row: 144B = 16B-aligned

typedef float    f32x4 __attribute__((ext_vector_type(4)));
typedef unsigned u32x2 __attribute__((ext_vector_type(2)));

__device__ __forceinline__ float fast_sigmoid(float x) {
    float e = __builtin_amdgcn_exp2f(-1.4426950408889634f * x);
    return __builtin_amdgcn_rcpf(1.0f + e);
}
__device__ __forceinline__ float fast_tanh(float x) {
    float e = __builtin_amdgcn_exp2f(2.8853900817779268f * x);
    return 1.0f - 2.0f * __builtin_amdgcn_rcpf(1.0f + e);
}

// Broadcast lane j's value to all lanes through an SGPR (zero memory latency).
__device__ __forceinline__ float rl(float v, int j) {
    return __uint_as_float(__builtin_amdgcn_readlane(__float_as_uint(v), j));
}

// Half-exchange of raw gate sums — VALIDATED round 10 (bit-exact vs shuffles).
#if __has_builtin(__builtin_amdgcn_permlane32_swap)
__device__ __forceinline__ void half_exchange(float g, bool, float& low_own, float& up_own) {
    u32x2 r = __builtin_amdgcn_permlane32_swap(__float_as_uint(g), __float_as_uint(g), false, false);
    low_own = __uint_as_float(r.x);
    up_own  = __uint_as_float(r.y);
}
#else
__device__ __forceinline__ void half_exchange(float g, bool lo, float& low_own, float& up_own) {
    const float p = __shfl_xor(g, 32, 64);
    low_own = lo ? g : p;
    up_own  = lo ? p : g;
}
#endif

// ROUND-10-VALIDATED DATAFLOW, LDS round-trip removed from the serial chain.
// One wave per batch element. Lane l owns W_hh rows l and l+64 (torch order
// i,f,g,o): lanes 0-31 (i_k,g_k), lanes 32-63 (f_k,o_k), k=lane&31. ALL lanes
// redundantly maintain the same c/h (validated r1/7/9/10) — so h_0..h_31 live
// in lanes 0..31 and the h-broadcast for the next step's dot is 32
// v_readlane ops into SGPRs (no LDS latency), consumed directly as the
// scalar operand of v_fma. x: lane l holds x[blk*64+l]; one readlane per
// step gives the uniform x_t (prefetched one block ahead). The LDS ring is
// WRITE-ONLY in the hot loop, feeding the bulk y-pass once per 64 steps
// (each lane computes one y with W_lin held uniform/SGPR). Single wave ->
// in-order DS pipe, no barriers.
__global__ __launch_bounds__(64, 1) void lstm_scan_kernel(
    const float* __restrict__ x,      // (B, 1, S)
    const float* __restrict__ W_ih,   // (128, 1)
    const float* __restrict__ W_hh,   // (128, 32)
    const float* __restrict__ b_ih,   // (128,)
    const float* __restrict__ b_hh,   // (128,)
    const float* __restrict__ W_lin,  // (1, 32)
    const float* __restrict__ b_lin,  // (1,)
    float* __restrict__ out)          // (B, 1, S)
{
    const int  b    = blockIdx.x;
    const int  lane = threadIdx.x;     // 0..63
    const int  k    = lane & 31;
    const bool lo   = (lane < 32);

    __shared__ __align__(16) float hlds[BSTEP * RSTRIDE];   // write-only ring (y-pass)

    // ---- one-time preload: W_hh rows lane, lane+64 as scalars (64 VGPRs) ----
    float w0[HID], w1[HID];
    {
        const f32x4* r0 = (const f32x4*)(W_hh + lane * HID);
        const f32x4* r1 = (const f32x4*)(W_hh + (lane + 64) * HID);
        #pragma unroll
        for (int q = 0; q < 8; ++q) {
            f32x4 v0 = r0[q], v1 = r1[q];
            w0[4*q+0] = v0.x; w0[4*q+1] = v0.y; w0[4*q+2] = v0.z; w0[4*q+3] = v0.w;
            w1[4*q+0] = v1.x; w1[4*q+1] = v1.y; w1[4*q+2] = v1.z; w1[4*q+3] = v1.w;
        }
    }
    const float bias0 = b_ih[lane]      + b_hh[lane];
    const float bias1 = b_ih[lane + 64] + b_hh[lane + 64];
    const float wih0  = W_ih[lane];
    const float wih1  = W_ih[lane + 64];
    const float blin  = b_lin[0];

    // W_lin: uniform loads -> scalar regs (same value in all lanes)
    float wls[HID];
    #pragma unroll
    for (int j = 0; j < HID; ++j) wls[j] = W_lin[j];

    float hcur = 0.0f, ccur = 0.0f;
    const float* __restrict__ xb = x   + (size_t)b * SLEN;
    float* __restrict__       ob = out + (size_t)b * SLEN;

    // x: lane l holds x[blk*BSTEP + l]; prefetched one block ahead
    float xcur = xb[lane];

    #pragma unroll 1
    for (int blk = 0; blk < NBLK; ++blk) {
        const int nb_ = (blk + 1 < NBLK) ? (blk + 1) : blk;
        float xnext = xb[nb_ * BSTEP + lane];   // issued early, consumed at block end

        #pragma unroll 1
        for (int i = 0; i < BSTEP / 4; ++i) {
            #pragma unroll
            for (int c4 = 0; c4 < 4; ++c4) {
                const int u  = 4 * i + c4;
                const float xt = rl(xcur, u);    // uniform x_t, no memory op

                // two 32-dots vs h (broadcast via readlane -> SGPR operand)
                float A0 = fmaf(xt, wih0, bias0), A1 = 0.0f;
                float B0 = fmaf(xt, wih1, bias1), B1 = 0.0f;
                #pragma unroll
                for (int j = 0; j < HID; j += 2) {
                    const float hj0 = rl(hcur, j);
                    const float hj1 = rl(hcur, j + 1);
                    A0 = fmaf(hj0, w0[j],     A0);
                    A1 = fmaf(hj1, w0[j + 1], A1);
                    B0 = fmaf(hj0, w1[j],     B0);
                    B1 = fmaf(hj1, w1[j + 1], B1);
                }
                const float g0 = A0 + A1;   // lower: i_k   upper: f_k
                const float g1 = B0 + B1;   // lower: g_k   upper: o_k

                float gi, gf, gg, go;
                half_exchange(g0, lo, gi, gf);
                half_exchange(g1, lo, gg, go);

                // ALL lanes redundantly maintain the same c (validated dataflow)
                ccur = fmaf(fast_sigmoid(gf), ccur, fast_sigmoid(gi) * fast_tanh(gg));
                hcur = fast_sigmoid(go) * fast_tanh(ccur);
                if (lo) hlds[u * RSTRIDE + k] = hcur;   // write-only ring (y-pass)
            }
        }

        // bulk y-pass: lane l computes y for step blk*64+l from ring slot l
        {
            const f32x4* h4 = (const f32x4*)(hlds + lane * RSTRIDE);
            float acc = blin;
            #pragma unroll
            for (int q = 0; q < 8; ++q) {
                const f32x4 hv = h4[q];
                acc = fmaf(hv.x, wls[4*q+0], acc);
                acc = fmaf(hv.y, wls[4*q+1], acc);
                acc = fmaf(hv.z, wls[4*q+2], acc);
                acc = fmaf(hv.w, wls[4*q+3], acc);
            }
            ob[blk * BSTEP + lane] = fast_tanh(acc);
        }

        xcur = xnext;
    }
}

extern "C" void kernel_launch(void* const* d_in, const int* in_sizes, int n_in,
                              void* d_out, int out_size, void* d_ws, size_t ws_size,
                              hipStream_t stream) {
    (void)d_ws; (void)ws_size; (void)in_sizes; (void)n_in; (void)out_size;
    const float* x     = (const float*)d_in[0];
    const float* W_ih  = (const float*)d_in[1];
    const float* W_hh  = (const float*)d_in[2];
    const float* b_ih  = (const float*)d_in[3];
    const float* b_hh  = (const float*)d_in[4];
    const float* W_lin = (const float*)d_in[5];
    const float* b_lin = (const float*)d_in[6];
    float* out = (float*)d_out;

    hipLaunchKernelGGL(lstm_scan_kernel, dim3(NB), dim3(64), 0, stream,
                       x, W_ih, W_hh, b_ih, b_hh, W_lin, b_lin, out);
}